// Round 1
// baseline (80.330 us; speedup 1.0000x reference)
//
#include <hip/hip_runtime.h>

#define IMG 512
#define NBATCH 32
#define TW 32
#define TH 32
#define PADR 5
#define IW (TW + 2*PADR)   /* 42 */
#define IH (TH + 2*PADR)   /* 42 */
#define SSTR (IW + 1)      /* 43: odd stride -> conflict-free column walks */
#define HSTR (TW + 1)      /* 33: odd stride -> conflict-free row-varying writes */

// sigma=1.5, 11-tap normalized Gaussian (numpy float64 -> float32)
#define GW_INIT { \
  0.0010283804f, 0.0075987583f, 0.0360007700f, 0.1093606900f, 0.2130055300f, \
  0.2660117200f, \
  0.2130055300f, 0.1093606900f, 0.0360007700f, 0.0075987583f, 0.0010283804f }

__global__ __launch_bounds__(256) void ssim_main(const float* __restrict__ img1,
                                                 const float* __restrict__ img2,
                                                 float* __restrict__ partials) {
    __shared__ float s1[IH][SSTR];
    __shared__ float s2[IH][SSTR];
    __shared__ float hb[5][IH][HSTR];
    __shared__ float red[4];

    constexpr float GW[11] = GW_INIT;
    const int tid = threadIdx.x;
    const int bx = blockIdx.x, by = blockIdx.y, b = blockIdx.z;
    const int x0 = bx * TW - PADR;
    const int y0 = by * TH - PADR;
    const float* p1 = img1 + (size_t)b * IMG * IMG;
    const float* p2 = img2 + (size_t)b * IMG * IMG;

    // ---- stage inputs (zero-padded halo) ----
    for (int idx = tid; idx < IH * IW; idx += 256) {
        int r = idx / IW, c = idx - r * IW;
        int gy = y0 + r, gx = x0 + c;
        bool ok = (gy >= 0) & (gy < IMG) & (gx >= 0) & (gx < IMG);
        long off = (long)gy * IMG + gx;
        float v1 = ok ? p1[off] : 0.f;
        float v2 = ok ? p2[off] : 0.f;
        s1[r][c] = v1;
        s2[r][c] = v2;
    }
    __syncthreads();

    // ---- horizontal pass: 5 fields, col-blocked by 8 ----
    // tasks: IH rows x 4 colgroups = 168 (single sweep, lanes->consecutive r)
    for (int task = tid; task < IH * 4; task += 256) {
        int r  = task % IH;
        int c0 = (task / IH) * 8;
        float i1[18], i2[18], q11[18], q22[18], q12[18];
#pragma unroll
        for (int u = 0; u < 18; ++u) {
            float a = s1[r][c0 + u];
            float bb = s2[r][c0 + u];
            i1[u] = a; i2[u] = bb;
            q11[u] = a * a; q22[u] = bb * bb; q12[u] = a * bb;
        }
#pragma unroll
        for (int k = 0; k < 8; ++k) {
            float a1 = 0.f, a2 = 0.f, a11 = 0.f, a22 = 0.f, a12 = 0.f;
#pragma unroll
            for (int u = 0; u < 11; ++u) {
                float w = GW[u];
                a1  += w * i1[k + u];
                a2  += w * i2[k + u];
                a11 += w * q11[k + u];
                a22 += w * q22[k + u];
                a12 += w * q12[k + u];
            }
            int c = c0 + k;
            hb[0][r][c] = a1;
            hb[1][r][c] = a2;
            hb[2][r][c] = a11;
            hb[3][r][c] = a22;
            hb[4][r][c] = a12;
        }
    }
    __syncthreads();

    // ---- vertical pass + SSIM map ----
    const int c  = tid & 31;
    const int r0 = (tid >> 5) * 4;   // 8 rowgroups x 4 rows
    float acc[4][5];
#pragma unroll
    for (int j = 0; j < 4; ++j)
#pragma unroll
        for (int q = 0; q < 5; ++q) acc[j][q] = 0.f;

#pragma unroll
    for (int t = 0; t < 14; ++t) {
        float v0 = hb[0][r0 + t][c];
        float v1 = hb[1][r0 + t][c];
        float v2 = hb[2][r0 + t][c];
        float v3 = hb[3][r0 + t][c];
        float v4 = hb[4][r0 + t][c];
#pragma unroll
        for (int j = 0; j < 4; ++j) {
            if (j <= t && t - j <= 10) {
                float w = GW[t - j];
                acc[j][0] += w * v0;
                acc[j][1] += w * v1;
                acc[j][2] += w * v2;
                acc[j][3] += w * v3;
                acc[j][4] += w * v4;
            }
        }
    }

    const float C1 = 0.0001f, C2 = 0.0009f;
    float local = 0.f;
#pragma unroll
    for (int j = 0; j < 4; ++j) {
        float mu1 = acc[j][0], mu2 = acc[j][1];
        float mu1sq = mu1 * mu1, mu2sq = mu2 * mu2, mu12 = mu1 * mu2;
        float sg1 = acc[j][2] - mu1sq;
        float sg2 = acc[j][3] - mu2sq;
        float sgx = acc[j][4] - mu12;
        float num = (2.f * mu12 + C1) * (2.f * sgx + C2);
        float den = (mu1sq + mu2sq + C1) * (sg1 + sg2 + C2);
        local += num * __builtin_amdgcn_rcpf(den);
    }

    // ---- block reduction -> partial ----
#pragma unroll
    for (int off = 32; off > 0; off >>= 1)
        local += __shfl_down(local, off, 64);
    if ((tid & 63) == 0) red[tid >> 6] = local;
    __syncthreads();
    if (tid == 0) {
        float s = red[0] + red[1] + red[2] + red[3];
        partials[((long)blockIdx.z * gridDim.y + blockIdx.y) * gridDim.x + blockIdx.x] = s;
    }
}

__global__ __launch_bounds__(256) void ssim_finalize(const float* __restrict__ partials,
                                                     int n, float* __restrict__ out) {
    __shared__ double red[4];
    double s = 0.0;
    for (int i = threadIdx.x; i < n; i += 256) s += (double)partials[i];
#pragma unroll
    for (int off = 32; off > 0; off >>= 1)
        s += __shfl_down(s, off, 64);
    if ((threadIdx.x & 63) == 0) red[threadIdx.x >> 6] = s;
    __syncthreads();
    if (threadIdx.x == 0) {
        double tot = red[0] + red[1] + red[2] + red[3];
        out[0] = (float)(1.0 - tot / (32.0 * 512.0 * 512.0));
    }
}

extern "C" void kernel_launch(void* const* d_in, const int* in_sizes, int n_in,
                              void* d_out, int out_size, void* d_ws, size_t ws_size,
                              hipStream_t stream) {
    const float* img1 = (const float*)d_in[0];
    const float* img2 = (const float*)d_in[1];
    float* out = (float*)d_out;
    float* partials = (float*)d_ws;

    dim3 grid(IMG / TW, IMG / TH, NBATCH);  // 16 x 16 x 32 = 8192 blocks
    ssim_main<<<grid, 256, 0, stream>>>(img1, img2, partials);
    ssim_finalize<<<1, 256, 0, stream>>>(partials, (IMG / TW) * (IMG / TH) * NBATCH, out);
}

// Round 2
// 61.149 us; speedup vs baseline: 1.3137x; 1.3137x over previous
//
#include <hip/hip_runtime.h>

#define IMG 512
#define NB 32
#define WOUT 118      /* output columns per block */
#define HTILE 64      /* output rows per block */
#define G 16          /* rows per chunk held in LDS */
#define NCHUNK (HTILE / G)
#define VSTR 132      /* LDS row stride: 132%32=4 -> b128 reads hit all banks */
#define GXT 5         /* ceil(512/118) */
#define GYT (IMG / HTILE)
#define NBLK (GXT * GYT * NB)

// sigma=1.5, 11-tap normalized Gaussian (numpy float64 -> float32); validated R1 (absmax 0.0)
#define GW_INIT { \
  0.0010283804f, 0.0075987583f, 0.0360007700f, 0.1093606900f, 0.2130055300f, \
  0.2660117200f, \
  0.2130055300f, 0.1093606900f, 0.0360007700f, 0.0075987583f, 0.0010283804f }

__global__ __launch_bounds__(256, 3) void ssim_main(const float* __restrict__ img1,
                                                    const float* __restrict__ img2,
                                                    float* __restrict__ partials) {
    __shared__ __attribute__((aligned(16))) float vf[5][G][VSTR];
    __shared__ float red[4];

    constexpr float GW[11] = GW_INIT;
    const int tid = threadIdx.x;
    const int bx = blockIdx.x, by = blockIdx.y, bz = blockIdx.z;
    const float* p1 = img1 + (size_t)bz * (IMG * IMG);
    const float* p2 = img2 + (size_t)bz * (IMG * IMG);
    const int x0 = bx * WOUT;
    const int y0 = by * HTILE;

    // vertical-phase ids: 128 columns x 2 row-halves
    const int vc = tid & 127;
    const int vhalf = tid >> 7;
    const int gxin = x0 + vc - 5;
    const bool okx = (gxin >= 0) & (gxin < IMG);
    const int gxc = okx ? gxin : 0;

    // horizontal-phase ids: 16 col-groups (span 8) x 16 rows
    const int ct = tid & 15;
    const int hg = tid >> 4;

    float local = 0.f;

    for (int chunk = 0; chunk < NCHUNK; ++chunk) {
        // ---------- vertical conv: global -> regs -> LDS ----------
        {
            const int yOutBase = y0 + chunk * G + vhalf * 8;
            float acc[8][5];
#pragma unroll
            for (int g = 0; g < 8; ++g)
#pragma unroll
                for (int f = 0; f < 5; ++f) acc[g][f] = 0.f;

#pragma unroll
            for (int j = 0; j < 18; ++j) {
                const int gy = yOutBase + j - 5;
                const bool ok = okx & (gy >= 0) & (gy < IMG);
                const int gyc = ok ? gy : 0;
                const float ra = p1[(size_t)gyc * IMG + gxc];
                const float rb = p2[(size_t)gyc * IMG + gxc];
                const float a = ok ? ra : 0.f;
                const float b = ok ? rb : 0.f;
                const float v0 = a, v1 = b, v2 = a * a, v3 = b * b, v4 = a * b;
#pragma unroll
                for (int u = 0; u < 11; ++u) {
                    const int g = j - u;   // input row j feeds output g with weight GW[u]
                    if (g >= 0 && g < 8) {
                        const float w = GW[u];
                        acc[g][0] += w * v0;
                        acc[g][1] += w * v1;
                        acc[g][2] += w * v2;
                        acc[g][3] += w * v3;
                        acc[g][4] += w * v4;
                    }
                }
            }
            const int gg = vhalf * 8;
#pragma unroll
            for (int g = 0; g < 8; ++g) {
#pragma unroll
                for (int f = 0; f < 5; ++f)
                    vf[f][gg + g][vc] = acc[g][f];
            }
        }
        __syncthreads();

        // ---------- horizontal conv (b128 LDS reads) + SSIM map ----------
        if (ct < 15) {
            float mu1[8], mu2[8], e11[8], e22[8], e12[8];
#define HPASS(FIELD, DST) { \
            float wnd[20]; \
            const float* bse = &vf[FIELD][hg][ct * 8]; \
            _Pragma("unroll") \
            for (int m = 0; m < 5; ++m) { \
                const float4 v4 = *reinterpret_cast<const float4*>(bse + 4 * m); \
                wnd[4*m+0] = v4.x; wnd[4*m+1] = v4.y; \
                wnd[4*m+2] = v4.z; wnd[4*m+3] = v4.w; } \
            _Pragma("unroll") \
            for (int k = 0; k < 8; ++k) { \
                float s = 0.f; \
                _Pragma("unroll") \
                for (int u = 0; u < 11; ++u) s += GW[u] * wnd[k + u]; \
                DST[k] = s; } }
            HPASS(0, mu1)
            HPASS(1, mu2)
            HPASS(2, e11)
            HPASS(3, e22)
            HPASS(4, e12)
#undef HPASS
            const float C1 = 0.0001f, C2 = 0.0009f;
#pragma unroll
            for (int k = 0; k < 8; ++k) {
                const int Xl = ct * 8 + k;
                const bool valid = (Xl < WOUT) & (x0 + Xl < IMG);
                const float m1 = mu1[k], m2 = mu2[k];
                const float m1s = m1 * m1, m2s = m2 * m2, m12 = m1 * m2;
                const float s1 = e11[k] - m1s, s2 = e22[k] - m2s, sx = e12[k] - m12;
                const float num = (2.f * m12 + C1) * (2.f * sx + C2);
                const float den = (m1s + m2s + C1) * (s1 + s2 + C2);
                const float v = num * __builtin_amdgcn_rcpf(den);
                local += valid ? v : 0.f;
            }
        }
        __syncthreads();
    }

    // ---------- block reduction ----------
#pragma unroll
    for (int off = 32; off > 0; off >>= 1)
        local += __shfl_down(local, off, 64);
    if ((tid & 63) == 0) red[tid >> 6] = local;
    __syncthreads();
    if (tid == 0) {
        const size_t bid = ((size_t)bz * GYT + by) * GXT + bx;
        partials[bid] = red[0] + red[1] + red[2] + red[3];
    }
}

__global__ __launch_bounds__(256) void ssim_finalize(const float* __restrict__ partials,
                                                     int n, float* __restrict__ out) {
    __shared__ double red[4];
    double s = 0.0;
    for (int i = threadIdx.x; i < n; i += 256) s += (double)partials[i];
#pragma unroll
    for (int off = 32; off > 0; off >>= 1)
        s += __shfl_down(s, off, 64);
    if ((threadIdx.x & 63) == 0) red[threadIdx.x >> 6] = s;
    __syncthreads();
    if (threadIdx.x == 0) {
        double tot = red[0] + red[1] + red[2] + red[3];
        out[0] = (float)(1.0 - tot / (32.0 * 512.0 * 512.0));
    }
}

extern "C" void kernel_launch(void* const* d_in, const int* in_sizes, int n_in,
                              void* d_out, int out_size, void* d_ws, size_t ws_size,
                              hipStream_t stream) {
    const float* img1 = (const float*)d_in[0];
    const float* img2 = (const float*)d_in[1];
    float* out = (float*)d_out;
    float* partials = (float*)d_ws;

    dim3 grid(GXT, GYT, NB);   // 5 x 8 x 32 = 1280 blocks
    ssim_main<<<grid, 256, 0, stream>>>(img1, img2, partials);
    ssim_finalize<<<1, 256, 0, stream>>>(partials, NBLK, out);
}

// Round 3
// 33.237 us; speedup vs baseline: 2.4169x; 1.8398x over previous
//
#include <hip/hip_runtime.h>

typedef _Float16 f16x8 __attribute__((ext_vector_type(8)));
typedef float f32x4 __attribute__((ext_vector_type(4)));

#define IMG 512
#define NB 32
#define OUTC 118
#define OUTR 32
#define GX 5
#define GY 16
#define NBLK (GX*GY*NB)
#define INSTR 56           /* lds_in slot stride (fp16): 112B -> 28 words, conflict-free b128 */
#define VSTR 136           /* lds_v col stride (fp16): 272B, 16B-aligned, 2-way worst */
#define VOFF (16*VSTR)

// sigma=1.5, 11-tap normalized Gaussian (validated R1/R2, absmax 0.0)
#define GW_LIST { 0.0010283804f, 0.0075987583f, 0.0360007700f, 0.1093606900f, \
  0.2130055300f, 0.2660117200f, 0.2130055300f, 0.1093606900f, 0.0360007700f, \
  0.0075987583f, 0.0010283804f }

__global__ __launch_bounds__(256) void ssim_mfma(const float* __restrict__ img1,
                                                 const float* __restrict__ img2,
                                                 float* __restrict__ partials) {
    // input strips, col-major per column (K=rows contiguous), fp16
    __shared__ _Float16 lds_in[2][128][INSTR];
    // v-conv output, row-major, fp16 (+pad cols 128..135 zeroed, +tail)
    __shared__ _Float16 lds_v[5*VOFF + 32];
    __shared__ _Float16 gwt[64];
    __shared__ float red[4];

    const int tid  = threadIdx.x;
    const int lane = tid & 63;
    const int lm   = lane & 15;
    const int kg   = lane >> 4;
    const int w    = tid >> 6;

    const int bx = blockIdx.x, by = blockIdx.y, bz = blockIdx.z;
    const float* __restrict__ p1 = img1 + (size_t)bz * (IMG*IMG);
    const float* __restrict__ p2 = img2 + (size_t)bz * (IMG*IMG);
    const int x0 = bx * OUTC;
    const int y0 = by * OUTR;

    // staging ids: 128 cols x 2 row-halves
    const int ci = tid & 127;
    const int hh = tid >> 7;
    const int gc = x0 - 5 + ci;
    const bool okc = (gc >= 0) && (gc < IMG);
    const int gcc  = okc ? gc : 0;

    // ---- strip-0 staging: slots [hh*16 .. hh*16+15]; real data only slots<26 ----
    {
        union { _Float16 h[16]; f16x8 v[2]; } ua, ub;
        const int slot0 = hh * 16;
#pragma unroll
        for (int p = 0; p < 16; ++p) {
            const int slot = slot0 + p;
            const int ar = y0 - 5 + slot;
            const bool ok = okc & (slot < 26) & (ar >= 0) & (ar < IMG);
            const int arc = ok ? ar : 0;
            float v1 = p1[arc*IMG + gcc];
            float v2 = p2[arc*IMG + gcc];
            ua.h[p] = (_Float16)(ok ? v1 : 0.f);
            ub.h[p] = (_Float16)(ok ? v2 : 0.f);
        }
        *(f16x8*)&lds_in[0][ci][slot0]   = ua.v[0];
        *(f16x8*)&lds_in[0][ci][slot0+8] = ua.v[1];
        *(f16x8*)&lds_in[1][ci][slot0]   = ub.v[0];
        *(f16x8*)&lds_in[1][ci][slot0+8] = ub.v[1];
        f16x8 z = {};
        *(f16x8*)&lds_in[0][ci][32 + hh*8] = z;   // zero slots 32..47
        *(f16x8*)&lds_in[1][ci][32 + hh*8] = z;
    }
    // ---- gaussian table + lds_v pad zeroing ----
    {
        const float GWc[11] = GW_LIST;
        if (tid < 64) {
            float wv = 0.f;
            const int t = tid - 16;
#pragma unroll
            for (int k = 0; k < 11; ++k) if (t == k) wv = GWc[k];
            gwt[tid] = (_Float16)wv;
        }
        f16x8 z = {};
        if (tid >= 64 && tid < 144) {          // 80 pad rows: cols 128..135
            const int u = tid - 64;
            const int f = u / 16, r = u % 16;
            *(f16x8*)&lds_v[f*VOFF + r*VSTR + 128] = z;
        } else if (tid >= 144 && tid < 148) {  // 32-elem tail
            *(f16x8*)&lds_v[5*VOFF + (tid-144)*8] = z;
        }
    }
    __syncthreads();

    // weight fragment: A[m=lm][k=kg*8+i] = GW[k-m]  (also serves as B[k][n=lm])
    union { _Float16 h[8]; f16x8 v; } wu;
#pragma unroll
    for (int i = 0; i < 8; ++i) wu.h[i] = gwt[16 + kg*8 + i - lm];

    float local = 0.f;
    const f32x4 zc = {0.f, 0.f, 0.f, 0.f};

    // stage V: weights(A) x data(B); D row=(kg*4+j), col=lm  -> lds_v row-major
    auto stage_v = [&](int sbase) {
#pragma unroll
        for (int q = 0; q < 2; ++q) {
            const int cb = 2*w + q;
            const f16x8 xf = *(const f16x8*)&lds_in[0][cb*16 + lm][sbase + kg*8];
            const f16x8 yf = *(const f16x8*)&lds_in[1][cb*16 + lm][sbase + kg*8];
            const f16x8 fr0 = xf, fr1 = yf;
            const f16x8 fr2 = xf*xf, fr3 = yf*yf, fr4 = xf*yf;
            const int colb = cb*16 + lm;
            const int rb = kg*4;
#define DO_F(F, FR) { \
            f32x4 d = __builtin_amdgcn_mfma_f32_16x16x32_f16(wu.v, FR, zc, 0, 0, 0); \
            lds_v[(F)*VOFF + (rb+0)*VSTR + colb] = (_Float16)d[0]; \
            lds_v[(F)*VOFF + (rb+1)*VSTR + colb] = (_Float16)d[1]; \
            lds_v[(F)*VOFF + (rb+2)*VSTR + colb] = (_Float16)d[2]; \
            lds_v[(F)*VOFF + (rb+3)*VSTR + colb] = (_Float16)d[3]; }
            DO_F(0, fr0) DO_F(1, fr1) DO_F(2, fr2) DO_F(3, fr3) DO_F(4, fr4)
#undef DO_F
        }
    };

    // stage H: data(A) x weights(B); D row=(kg*4+j)=out row, col=lm=out col; + SSIM
    auto stage_h = [&]() {
#pragma unroll
        for (int q = 0; q < 2; ++q) {
            const int xx = 2*w + q;
            const int cb2 = xx*16 + kg*8;
            const f16x8 a0 = *(const f16x8*)&lds_v[0*VOFF + lm*VSTR + cb2];
            const f16x8 a1 = *(const f16x8*)&lds_v[1*VOFF + lm*VSTR + cb2];
            const f16x8 a2 = *(const f16x8*)&lds_v[2*VOFF + lm*VSTR + cb2];
            const f16x8 a3 = *(const f16x8*)&lds_v[3*VOFF + lm*VSTR + cb2];
            const f16x8 a4 = *(const f16x8*)&lds_v[4*VOFF + lm*VSTR + cb2];
            const f32x4 d0 = __builtin_amdgcn_mfma_f32_16x16x32_f16(a0, wu.v, zc, 0,0,0);
            const f32x4 d1 = __builtin_amdgcn_mfma_f32_16x16x32_f16(a1, wu.v, zc, 0,0,0);
            const f32x4 d2 = __builtin_amdgcn_mfma_f32_16x16x32_f16(a2, wu.v, zc, 0,0,0);
            const f32x4 d3 = __builtin_amdgcn_mfma_f32_16x16x32_f16(a3, wu.v, zc, 0,0,0);
            const f32x4 d4 = __builtin_amdgcn_mfma_f32_16x16x32_f16(a4, wu.v, zc, 0,0,0);
            const int X = xx*16 + lm;
            const bool valid = (X < OUTC) & (x0 + X < IMG);
            float s4 = 0.f;
#pragma unroll
            for (int j = 0; j < 4; ++j) {
                const float mu1 = d0[j], mu2 = d1[j];
                const float m11 = mu1*mu1, m22 = mu2*mu2, m12 = mu1*mu2;
                const float s1 = d2[j] - m11, s2 = d3[j] - m22, sx = d4[j] - m12;
                const float num = (2.f*m12 + 1e-4f) * (2.f*sx + 9e-4f);
                const float den = (m11 + m22 + 1e-4f) * (s1 + s2 + 9e-4f);
                s4 += num * __builtin_amdgcn_rcpf(den);
            }
            local += valid ? s4 : 0.f;
        }
    };

    // ================= strip 0 =================
    stage_v(0);
    __syncthreads();

    // prefetch strip-1 rows (slots 26..41, abs y0+21..y0+36) into regs
    float pa[8], pb[8];
    {
        const int ab = y0 + 21 + hh*8;
#pragma unroll
        for (int p = 0; p < 8; ++p) {
            const int ar = ab + p;
            const bool ok = okc & (ar < IMG);
            const int arc = ok ? ar : 0;
            float v1 = p1[arc*IMG + gcc];
            float v2 = p2[arc*IMG + gcc];
            pa[p] = ok ? v1 : 0.f;
            pb[p] = ok ? v2 : 0.f;
        }
    }

    stage_h();

    // write strip-1 into lds_in (safe: all waves past stage_v(0) barrier)
    {
        const int sl = 26 + hh*8;
#pragma unroll
        for (int p = 0; p < 8; p += 2) {
            union { _Float16 h[2]; uint32_t u; } q1, q2;
            q1.h[0] = (_Float16)pa[p]; q1.h[1] = (_Float16)pa[p+1];
            q2.h[0] = (_Float16)pb[p]; q2.h[1] = (_Float16)pb[p+1];
            *(uint32_t*)&lds_in[0][ci][sl + p] = q1.u;
            *(uint32_t*)&lds_in[1][ci][sl + p] = q2.u;
        }
    }
    __syncthreads();

    // ================= strip 1 =================
    stage_v(16);
    __syncthreads();
    stage_h();

    // ---- block reduction ----
#pragma unroll
    for (int off = 32; off > 0; off >>= 1)
        local += __shfl_down(local, off, 64);
    if (lane == 0) red[w] = local;
    __syncthreads();
    if (tid == 0) {
        partials[(size_t)((bz*GY + by)*GX + bx)] = red[0] + red[1] + red[2] + red[3];
    }
}

__global__ __launch_bounds__(256) void ssim_finalize(const float* __restrict__ partials,
                                                     int n, float* __restrict__ out) {
    __shared__ double red[4];
    double s = 0.0;
    for (int i = threadIdx.x; i < n; i += 256) s += (double)partials[i];
#pragma unroll
    for (int off = 32; off > 0; off >>= 1)
        s += __shfl_down(s, off, 64);
    if ((threadIdx.x & 63) == 0) red[threadIdx.x >> 6] = s;
    __syncthreads();
    if (threadIdx.x == 0) {
        double tot = red[0] + red[1] + red[2] + red[3];
        out[0] = (float)(1.0 - tot / (32.0 * 512.0 * 512.0));
    }
}

extern "C" void kernel_launch(void* const* d_in, const int* in_sizes, int n_in,
                              void* d_out, int out_size, void* d_ws, size_t ws_size,
                              hipStream_t stream) {
    const float* img1 = (const float*)d_in[0];
    const float* img2 = (const float*)d_in[1];
    float* out = (float*)d_out;
    float* partials = (float*)d_ws;

    dim3 grid(GX, GY, NB);   // 5 x 16 x 32 = 2560 blocks
    ssim_mfma<<<grid, 256, 0, stream>>>(img1, img2, partials);
    ssim_finalize<<<1, 256, 0, stream>>>(partials, NBLK, out);
}

// Round 5
// 32.664 us; speedup vs baseline: 2.4592x; 1.0175x over previous
//
#include <hip/hip_runtime.h>

typedef _Float16 f16x8 __attribute__((ext_vector_type(8)));
typedef _Float16 f16x4 __attribute__((ext_vector_type(4)));
typedef __fp16 fp16x2 __attribute__((ext_vector_type(2)));
typedef float f32x4 __attribute__((ext_vector_type(4)));

#define IMG 512
#define NB 32
#define OUTC 118
#define OUTR 32
#define GX 5
#define GY 16
#define NBLK (GX*GY*NB)
#define INSTR 48           /* lds_in slot stride (fp16): 96B, 16B-aligned rows */
#define VSTR 136           /* lds_v col stride (fp16): 272B, 16B-aligned rows */
#define VOFF (16*VSTR)

// sigma=1.5, 11-tap normalized Gaussian (validated R1-R3, absmax 0.0)
#define GW_LIST { 0.0010283804f, 0.0075987583f, 0.0360007700f, 0.1093606900f, \
  0.2130055300f, 0.2660117200f, 0.2130055300f, 0.1093606900f, 0.0360007700f, \
  0.0075987583f, 0.0010283804f }

__global__ __launch_bounds__(256, 3) void ssim_mfma(const float* __restrict__ img1,
                                                    const float* __restrict__ img2,
                                                    float* __restrict__ partials) {
    // input, col-major per column (K=rows contiguous), fp16; slots 42..47 zero
    __shared__ _Float16 lds_in[2][128][INSTR];
    // v-conv output V[row][col], row-major fp16 (+pad cols 128..135 zeroed, +tail)
    __shared__ _Float16 lds_v[5*VOFF + 32];
    __shared__ _Float16 gwt[64];
    __shared__ float red[4];

    const int tid  = threadIdx.x;
    const int lane = tid & 63;
    const int lm   = lane & 15;
    const int kg   = lane >> 4;
    const int w    = tid >> 6;

    const int bx = blockIdx.x, by = blockIdx.y, bz = blockIdx.z;
    const float* __restrict__ p1 = img1 + (size_t)bz * (IMG*IMG);
    const float* __restrict__ p2 = img2 + (size_t)bz * (IMG*IMG);
    const int x0 = bx * OUTC;
    const int y0 = by * OUTR;

    // staging ids: 128 cols x 2 slot-halves (24 slots each)
    const int ci = tid & 127;
    const int hh = tid >> 7;
    const int gc = x0 - 5 + ci;
    const bool okc = (gc >= 0) && (gc < IMG);
    const int gcc  = okc ? gc : 0;

    // ---- single-pass staging: 42 real rows (y0-5 .. y0+36), slots 42..47 zero ----
    {
        union { _Float16 h[24]; f16x8 v[3]; } ua, ub;
        const int slot0 = hh * 24;
#pragma unroll
        for (int p = 0; p < 24; ++p) {
            const int slot = slot0 + p;
            const int ar = y0 - 5 + slot;
            const bool ok = okc & (slot < 42) & (ar >= 0) & (ar < IMG);
            const int arc = ok ? ar : 0;
            float v1 = p1[arc*IMG + gcc];
            float v2 = p2[arc*IMG + gcc];
            ua.h[p] = (_Float16)(ok ? v1 : 0.f);
            ub.h[p] = (_Float16)(ok ? v2 : 0.f);
        }
#pragma unroll
        for (int m = 0; m < 3; ++m) {
            *(f16x8*)&lds_in[0][ci][slot0 + 8*m] = ua.v[m];
            *(f16x8*)&lds_in[1][ci][slot0 + 8*m] = ub.v[m];
        }
    }
    // ---- gaussian table + lds_v pad zeroing (keeps stray reads finite) ----
    {
        const float GWc[11] = GW_LIST;
        if (tid < 64) {
            float wv = 0.f;
            const int t = tid - 16;
#pragma unroll
            for (int k = 0; k < 11; ++k) if (t == k) wv = GWc[k];
            gwt[tid] = (_Float16)wv;
        }
        f16x8 z = {};
        if (tid >= 64 && tid < 144) {          // 80 pad rows: cols 128..135
            const int u = tid - 64;
            const int f = u / 16, r = u % 16;
            *(f16x8*)&lds_v[f*VOFF + r*VSTR + 128] = z;
        } else if (tid >= 144 && tid < 148) {  // 32-elem tail
            *(f16x8*)&lds_v[5*VOFF + (tid-144)*8] = z;
        }
    }
    __syncthreads();

    // banded weight fragment: serves as B[k][n]=GW[k-n] for BOTH conv stages
    union { _Float16 h[8]; f16x8 v; } wu;
#pragma unroll
    for (int i = 0; i < 8; ++i) wu.h[i] = gwt[16 + kg*8 + i - lm];

    float local = 0.f;
    const f32x4 zc = {0.f, 0.f, 0.f, 0.f};

    // stage V: A = X^T (data, b128 from col-major lds_in), B = weights.
    // D[m=col][n=out_row]: lane holds out_row=lm, cols kg*4+j  -> one b64 per field
    auto stage_v = [&](int sbase) {
#pragma unroll
        for (int q = 0; q < 2; ++q) {
            const int cb = 2*w + q;
            const f16x8 xf = *(const f16x8*)&lds_in[0][cb*16 + lm][sbase + kg*8];
            const f16x8 yf = *(const f16x8*)&lds_in[1][cb*16 + lm][sbase + kg*8];
            const f16x8 fr0 = xf, fr1 = yf;
            const f16x8 fr2 = xf*xf, fr3 = yf*yf, fr4 = xf*yf;
            const int cbase = cb*16 + kg*4;
#define DO_F(F, FR) { \
            const f32x4 d = __builtin_amdgcn_mfma_f32_16x16x32_f16(FR, wu.v, zc, 0, 0, 0); \
            union { fp16x2 p[2]; f16x4 v4; } pk; \
            pk.p[0] = __builtin_amdgcn_cvt_pkrtz(d[0], d[1]); \
            pk.p[1] = __builtin_amdgcn_cvt_pkrtz(d[2], d[3]); \
            *(f16x4*)&lds_v[(F)*VOFF + lm*VSTR + cbase] = pk.v4; }
            DO_F(0, fr0) DO_F(1, fr1) DO_F(2, fr2) DO_F(3, fr3) DO_F(4, fr4)
#undef DO_F
        }
    };

    // stage H: A = V rows (b128, k=cols contiguous), B = weights; + SSIM map
    auto stage_h = [&]() {
#pragma unroll
        for (int q = 0; q < 2; ++q) {
            const int xx = 2*w + q;
            const int cb2 = xx*16 + kg*8;
            const f16x8 a0 = *(const f16x8*)&lds_v[0*VOFF + lm*VSTR + cb2];
            const f16x8 a1 = *(const f16x8*)&lds_v[1*VOFF + lm*VSTR + cb2];
            const f16x8 a2 = *(const f16x8*)&lds_v[2*VOFF + lm*VSTR + cb2];
            const f16x8 a3 = *(const f16x8*)&lds_v[3*VOFF + lm*VSTR + cb2];
            const f16x8 a4 = *(const f16x8*)&lds_v[4*VOFF + lm*VSTR + cb2];
            const f32x4 d0 = __builtin_amdgcn_mfma_f32_16x16x32_f16(a0, wu.v, zc, 0,0,0);
            const f32x4 d1 = __builtin_amdgcn_mfma_f32_16x16x32_f16(a1, wu.v, zc, 0,0,0);
            const f32x4 d2 = __builtin_amdgcn_mfma_f32_16x16x32_f16(a2, wu.v, zc, 0,0,0);
            const f32x4 d3 = __builtin_amdgcn_mfma_f32_16x16x32_f16(a3, wu.v, zc, 0,0,0);
            const f32x4 d4 = __builtin_amdgcn_mfma_f32_16x16x32_f16(a4, wu.v, zc, 0,0,0);
            const int X = xx*16 + lm;
            const bool valid = (X < OUTC) & (x0 + X < IMG);
            float s4 = 0.f;
#pragma unroll
            for (int j = 0; j < 4; ++j) {
                const float mu1 = d0[j], mu2 = d1[j];
                const float m11 = mu1*mu1, m22 = mu2*mu2, m12 = mu1*mu2;
                const float s1 = d2[j] - m11, s2 = d3[j] - m22, sx = d4[j] - m12;
                const float num = (2.f*m12 + 1e-4f) * (2.f*sx + 9e-4f);
                const float den = (m11 + m22 + 1e-4f) * (s1 + s2 + 9e-4f);
                s4 += num * __builtin_amdgcn_rcpf(den);
            }
            local += valid ? s4 : 0.f;
        }
    };

    // ================= strip 0 (out rows y0..y0+15) =================
    stage_v(0);
    __syncthreads();
    stage_h();
    __syncthreads();
    // ================= strip 1 (out rows y0+16..y0+31) ==============
    stage_v(16);
    __syncthreads();
    stage_h();

    // ---- block reduction ----
#pragma unroll
    for (int off = 32; off > 0; off >>= 1)
        local += __shfl_down(local, off, 64);
    if (lane == 0) red[w] = local;
    __syncthreads();
    if (tid == 0) {
        partials[(size_t)((bz*GY + by)*GX + bx)] = red[0] + red[1] + red[2] + red[3];
    }
}

__global__ __launch_bounds__(256) void ssim_finalize(const float* __restrict__ partials,
                                                     int n, float* __restrict__ out) {
    __shared__ double red[4];
    double s = 0.0;
    for (int i = threadIdx.x; i < n; i += 256) s += (double)partials[i];
#pragma unroll
    for (int off = 32; off > 0; off >>= 1)
        s += __shfl_down(s, off, 64);
    if ((threadIdx.x & 63) == 0) red[threadIdx.x >> 6] = s;
    __syncthreads();
    if (threadIdx.x == 0) {
        double tot = red[0] + red[1] + red[2] + red[3];
        out[0] = (float)(1.0 - tot / (32.0 * 512.0 * 512.0));
    }
}

extern "C" void kernel_launch(void* const* d_in, const int* in_sizes, int n_in,
                              void* d_out, int out_size, void* d_ws, size_t ws_size,
                              hipStream_t stream) {
    const float* img1 = (const float*)d_in[0];
    const float* img2 = (const float*)d_in[1];
    float* out = (float*)d_out;
    float* partials = (float*)d_ws;

    dim3 grid(GX, GY, NB);   // 5 x 16 x 32 = 2560 blocks
    ssim_mfma<<<grid, 256, 0, stream>>>(img1, img2, partials);
    ssim_finalize<<<1, 256, 0, stream>>>(partials, NBLK, out);
}